// Round 2
// baseline (1762.507 us; speedup 1.0000x reference)
//
#include <hip/hip_runtime.h>
#include <cstdint>
#include <cstddef>

#define B_ 16
#define S_ 512
#define D_ 512
#define H_ 8
#define DK_ 64
#define NL_ 6
#define DFF_ 2048

typedef float f32x4 __attribute__((ext_vector_type(4)));
typedef __bf16 bf16x8 __attribute__((ext_vector_type(8)));
typedef unsigned short u16x8 __attribute__((ext_vector_type(8)));

__device__ __forceinline__ unsigned short f2bf(float f) {
  unsigned u = __builtin_bit_cast(unsigned, f);
  unsigned r = (u + 0x7FFFu + ((u >> 16) & 1u)) >> 16;  // RNE
  return (unsigned short)r;
}

// ---------------- positional encoding add: xo = x + pe2d ----------------
__global__ __launch_bounds__(256) void pe_add_kernel(const float* __restrict__ x,
                                                     const float* __restrict__ coords,
                                                     const float* __restrict__ cls_pe,
                                                     float* __restrict__ xo) {
  int idx = blockIdx.x * 256 + threadIdx.x;
  int d = idx & (D_ - 1);
  int s = (idx >> 9) & (S_ - 1);
  float pe;
  if (s == 0) {
    pe = cls_pe[d];
  } else {
    float c = coords[(s - 1) * 2 + (d >= 256 ? 1 : 0)];
    int dd = d & 255;
    int t = dd >> 1;
    // div[t] = exp(-t * ln(10000)/128)
    float ang = c * expf((float)t * -0.07195578415606394f);
    pe = (dd & 1) ? cosf(ang) : sinf(ang);
  }
  xo[idx] = x[idx] + pe;
}

// ---------------- relative position bias table [H][S][S] ----------------
__global__ __launch_bounds__(256) void bias_kernel(const float* __restrict__ coords,
                                                   const float* __restrict__ emb,
                                                   float* __restrict__ bias) {
  int idx = blockIdx.x * 256 + threadIdx.x;  // i*S + j
  int j = idx & (S_ - 1), i = idx >> 9;
  float v[H_];
  if (i == 0 || j == 0) {
#pragma unroll
    for (int h = 0; h < H_; h++) v[h] = 0.f;
  } else {
    float dx = coords[(i - 1) * 2] - coords[(j - 1) * 2];
    float dy = coords[(i - 1) * 2 + 1] - coords[(j - 1) * 2 + 1];
    float dist = sqrtf(dx * dx + dy * dy);
    float t = fminf(dist / 10.0f, 1.0f) * 31.0f;
    int bkt = (int)t;
#pragma unroll
    for (int h = 0; h < H_; h++) v[h] = emb[bkt * H_ + h];
  }
#pragma unroll
  for (int h = 0; h < H_; h++) bias[(size_t)h * S_ * S_ + idx] = v[h];
}

// ---------------- transpose + fp32->bf16: dst[c][r] = src[r][c] ----------------
__global__ __launch_bounds__(256) void transpose_cvt(const float* __restrict__ src,
                                                     unsigned short* __restrict__ dst,
                                                     int R, int C) {
  src += (size_t)blockIdx.z * R * C;
  dst += (size_t)blockIdx.z * R * C;
  __shared__ float tile[32][33];
  int tx = threadIdx.x & 31, ty = threadIdx.x >> 5;  // 32 x 8
  int c0 = blockIdx.x * 32, r0 = blockIdx.y * 32;
#pragma unroll
  for (int i = 0; i < 32; i += 8)
    tile[ty + i][tx] = src[(size_t)(r0 + ty + i) * C + c0 + tx];
  __syncthreads();
#pragma unroll
  for (int i = 0; i < 32; i += 8)
    dst[(size_t)(c0 + ty + i) * R + r0 + tx] = f2bf(tile[tx][ty + i]);
}

// ---------------- LayerNorm: one wave per row of 512 ----------------
// OUTMODE 0: bf16 out; 1: fp32 out (supports in-place)
template <int OUTMODE>
__global__ __launch_bounds__(256) void ln_kernel(const float* __restrict__ x,
                                                 const float* __restrict__ g,
                                                 const float* __restrict__ be,
                                                 void* __restrict__ out) {
  int wid = threadIdx.x >> 6, l = threadIdx.x & 63;
  size_t row = (size_t)blockIdx.x * 4 + wid;
  const float4* xr = reinterpret_cast<const float4*>(x + row * D_);
  float4 a = xr[l * 2], c = xr[l * 2 + 1];
  float s = a.x + a.y + a.z + a.w + c.x + c.y + c.z + c.w;
  float sq = a.x * a.x + a.y * a.y + a.z * a.z + a.w * a.w +
             c.x * c.x + c.y * c.y + c.z * c.z + c.w * c.w;
#pragma unroll
  for (int m = 1; m < 64; m <<= 1) {
    s += __shfl_xor(s, m);
    sq += __shfl_xor(sq, m);
  }
  float mean = s * (1.0f / D_);
  float var = sq * (1.0f / D_) - mean * mean;
  float rstd = rsqrtf(var + 1e-5f);
  const float4* gp = reinterpret_cast<const float4*>(g);
  const float4* bp = reinterpret_cast<const float4*>(be);
  float4 g0 = gp[l * 2], g1 = gp[l * 2 + 1];
  float4 b0 = bp[l * 2], b1 = bp[l * 2 + 1];
  float y[8];
  y[0] = (a.x - mean) * rstd * g0.x + b0.x;
  y[1] = (a.y - mean) * rstd * g0.y + b0.y;
  y[2] = (a.z - mean) * rstd * g0.z + b0.z;
  y[3] = (a.w - mean) * rstd * g0.w + b0.w;
  y[4] = (c.x - mean) * rstd * g1.x + b1.x;
  y[5] = (c.y - mean) * rstd * g1.y + b1.y;
  y[6] = (c.z - mean) * rstd * g1.z + b1.z;
  y[7] = (c.w - mean) * rstd * g1.w + b1.w;
  if (OUTMODE == 0) {
    u16x8 o;
#pragma unroll
    for (int j = 0; j < 8; j++) o[j] = f2bf(y[j]);
    *reinterpret_cast<u16x8*>((unsigned short*)out + row * D_ + l * 8) = o;
  } else {
    float4 o0 = {y[0], y[1], y[2], y[3]};
    float4 o1 = {y[4], y[5], y[6], y[7]};
    float4* op = reinterpret_cast<float4*>((float*)out + row * D_ + l * 8);
    op[0] = o0;
    op[1] = o1;
  }
}

// ---------------- GEMM: C = A[M,K](bf16) @ BT[N,K]^T(bf16) + bias ----------------
// 128x128 tile, BK=64, 4 waves (2x2), mfma_f32_16x16x32_bf16.
// EPI 0: bf16 out + bias      EPI 1: fp32 resid += out + bias
// EPI 2: gelu(out+bias) bf16  EPI 3: V-transpose write [b,h,dk,s] bf16
template <int EPI>
__global__ __launch_bounds__(256) void gemm_bt(const unsigned short* __restrict__ A,
                                               const unsigned short* __restrict__ BT,
                                               const float* __restrict__ bias,
                                               unsigned short* __restrict__ outb,
                                               float* __restrict__ resid,
                                               int M, int N, int K) {
  __shared__ __align__(16) unsigned short As[128][72];
  __shared__ __align__(16) unsigned short Bs[128][72];
  int tid = threadIdx.x;
  int l = tid & 63, wid = tid >> 6;
  int wr = wid >> 1, wc = wid & 1;
  int m0 = blockIdx.y * 128, n0 = blockIdx.x * 128;
  int lr = l & 15, lk = (l >> 4) * 8;

  f32x4 acc[4][4];
#pragma unroll
  for (int m = 0; m < 4; m++)
#pragma unroll
    for (int n = 0; n < 4; n++) acc[m][n] = f32x4{0.f, 0.f, 0.f, 0.f};

  int srow = tid >> 3;        // 0..31
  int scol = (tid & 7) * 8;   // 0..56
  for (int k0 = 0; k0 < K; k0 += 64) {
    __syncthreads();
#pragma unroll
    for (int p = 0; p < 4; p++) {
      int r = p * 32 + srow;
      *reinterpret_cast<u16x8*>(&As[r][scol]) =
          *reinterpret_cast<const u16x8*>(&A[(size_t)(m0 + r) * K + k0 + scol]);
      *reinterpret_cast<u16x8*>(&Bs[r][scol]) =
          *reinterpret_cast<const u16x8*>(&BT[(size_t)(n0 + r) * K + k0 + scol]);
    }
    __syncthreads();
#pragma unroll
    for (int ks = 0; ks < 2; ks++) {
      bf16x8 af[4], bfr[4];
#pragma unroll
      for (int m = 0; m < 4; m++)
        af[m] = *reinterpret_cast<const bf16x8*>(&As[wr * 64 + m * 16 + lr][ks * 32 + lk]);
#pragma unroll
      for (int n = 0; n < 4; n++)
        bfr[n] = *reinterpret_cast<const bf16x8*>(&Bs[wc * 64 + n * 16 + lr][ks * 32 + lk]);
#pragma unroll
      for (int m = 0; m < 4; m++)
#pragma unroll
        for (int n = 0; n < 4; n++)
          acc[m][n] = __builtin_amdgcn_mfma_f32_16x16x32_bf16(af[m], bfr[n], acc[m][n], 0, 0, 0);
    }
  }
  // epilogue: C/D layout col=lane&15, row=(lane>>4)*4+rr
#pragma unroll
  for (int m = 0; m < 4; m++) {
#pragma unroll
    for (int n = 0; n < 4; n++) {
      int gc = n0 + wc * 64 + n * 16 + lr;
      float bv = bias[gc];
#pragma unroll
      for (int rr = 0; rr < 4; rr++) {
        int gr = m0 + wr * 64 + m * 16 + (l >> 4) * 4 + rr;
        float v = acc[m][n][rr] + bv;
        if (EPI == 0) {
          outb[(size_t)gr * N + gc] = f2bf(v);
        } else if (EPI == 1) {
          resid[(size_t)gr * N + gc] += v;
        } else if (EPI == 2) {
          float gl = 0.5f * v * (1.0f + erff(v * 0.70710678118654752f));
          outb[(size_t)gr * N + gc] = f2bf(gl);
        } else {
          int h = gc >> 6, dd = gc & 63, bb = gr >> 9, ss = gr & 511;
          outb[((size_t)((bb * H_ + h) * DK_ + dd)) * S_ + ss] = f2bf(v);
        }
      }
    }
  }
}

// ---------------- attention: block = (64 q-rows, b*h), 4 waves x 16 rows ----------------
__global__ __launch_bounds__(256) void attn_kernel(const unsigned short* __restrict__ Q,
                                                   const unsigned short* __restrict__ K,
                                                   const unsigned short* __restrict__ VT,
                                                   const float* __restrict__ bias,
                                                   const unsigned char* __restrict__ mask,
                                                   unsigned short* __restrict__ O) {
  __shared__ __align__(16) unsigned short P[4][16][520];  // per-wave private P tile
  int tid = threadIdx.x;
  int wid = tid >> 6, l = tid & 63;
  int bh = blockIdx.y;
  int b = bh >> 3, h = bh & 7;
  int q0 = blockIdx.x * 64 + wid * 16;
  int lr = l & 15;
  int lk = (l >> 4) * 8;
  int rb = (l >> 4) * 4;

  const unsigned short* qp = Q + (size_t)(b * S_ + q0 + lr) * D_ + h * DK_ + lk;
  bf16x8 aq0 = *reinterpret_cast<const bf16x8*>(qp);
  bf16x8 aq1 = *reinterpret_cast<const bf16x8*>(qp + 32);

  f32x4 acc[32];
#pragma unroll
  for (int n = 0; n < 32; n++) acc[n] = f32x4{0.f, 0.f, 0.f, 0.f};

  const unsigned short* kp = K + (size_t)(b * S_ + lr) * D_ + h * DK_ + lk;
#pragma unroll
  for (int n = 0; n < 32; n++) {
    bf16x8 k0 = *reinterpret_cast<const bf16x8*>(kp + (size_t)n * 16 * D_);
    bf16x8 k1 = *reinterpret_cast<const bf16x8*>(kp + (size_t)n * 16 * D_ + 32);
    acc[n] = __builtin_amdgcn_mfma_f32_16x16x32_bf16(aq0, k0, acc[n], 0, 0, 0);
    acc[n] = __builtin_amdgcn_mfma_f32_16x16x32_bf16(aq1, k1, acc[n], 0, 0, 0);
  }

  // scale + bias + mask, running row max
  float mx[4] = {-3.0e38f, -3.0e38f, -3.0e38f, -3.0e38f};
  const float* bp = bias + ((size_t)h * S_ + q0 + rb) * S_;
#pragma unroll
  for (int n = 0; n < 32; n++) {
    int sc = n * 16 + lr;
    bool msk = mask[b * S_ + sc] != 0;
#pragma unroll
    for (int rr = 0; rr < 4; rr++) {
      float v = acc[n][rr] * 0.125f + bp[(size_t)rr * S_ + sc];
      v = msk ? -1e9f : v;
      acc[n][rr] = v;
      mx[rr] = fmaxf(mx[rr], v);
    }
  }
#pragma unroll
  for (int rr = 0; rr < 4; rr++) {
#pragma unroll
    for (int m = 1; m < 16; m <<= 1) mx[rr] = fmaxf(mx[rr], __shfl_xor(mx[rr], m));
  }
  float sm[4] = {0.f, 0.f, 0.f, 0.f};
#pragma unroll
  for (int n = 0; n < 32; n++) {
#pragma unroll
    for (int rr = 0; rr < 4; rr++) {
      float p = expf(acc[n][rr] - mx[rr]);
      acc[n][rr] = p;
      sm[rr] += p;
    }
  }
#pragma unroll
  for (int rr = 0; rr < 4; rr++) {
#pragma unroll
    for (int m = 1; m < 16; m <<= 1) sm[rr] += __shfl_xor(sm[rr], m);
    sm[rr] = 1.0f / sm[rr];
  }
#pragma unroll
  for (int n = 0; n < 32; n++) {
#pragma unroll
    for (int rr = 0; rr < 4; rr++)
      P[wid][rb + rr][n * 16 + lr] = f2bf(acc[n][rr] * sm[rr]);
  }

  // PV: wave reads only its own P rows -> in-wave lgkmcnt ordering suffices
  f32x4 ao[4];
#pragma unroll
  for (int n = 0; n < 4; n++) ao[n] = f32x4{0.f, 0.f, 0.f, 0.f};
  const unsigned short* vp = VT + (size_t)(bh * DK_ + lr) * S_ + lk;
#pragma unroll 4
  for (int kk = 0; kk < 16; kk++) {
    bf16x8 pa = *reinterpret_cast<const bf16x8*>(&P[wid][lr][kk * 32 + lk]);
#pragma unroll
    for (int n = 0; n < 4; n++) {
      bf16x8 vb = *reinterpret_cast<const bf16x8*>(vp + (size_t)n * 16 * S_ + kk * 32);
      ao[n] = __builtin_amdgcn_mfma_f32_16x16x32_bf16(pa, vb, ao[n], 0, 0, 0);
    }
  }
#pragma unroll
  for (int n = 0; n < 4; n++)
#pragma unroll
    for (int rr = 0; rr < 4; rr++)
      O[(size_t)(b * S_ + q0 + rb + rr) * D_ + h * DK_ + n * 16 + lr] = f2bf(ao[n][rr]);
}

// ---------------- launch ----------------
extern "C" void kernel_launch(void* const* d_in, const int* in_sizes, int n_in,
                              void* d_out, int out_size, void* d_ws, size_t ws_size,
                              hipStream_t stream) {
  const float* x = (const float*)d_in[0];
  const float* coords = (const float*)d_in[1];
  const float* cls_pe = (const float*)d_in[2];
  const float* bias_emb = (const float*)d_in[3];
  const float* attn_w = (const float*)d_in[4];
  const float* attn_b = (const float*)d_in[5];
  const float* ff_w1 = (const float*)d_in[6];
  const float* ff_b1 = (const float*)d_in[7];
  const float* ff_w2 = (const float*)d_in[8];
  const float* ff_b2 = (const float*)d_in[9];
  const float* ln_g = (const float*)d_in[10];
  const float* ln_b = (const float*)d_in[11];
  const float* norm_g = (const float*)d_in[12];
  const float* norm_b = (const float*)d_in[13];
  const float* norm2_g = (const float*)d_in[14];
  const float* norm2_b = (const float*)d_in[15];
  const unsigned char* mask = (const unsigned char*)d_in[16];

  char* ws = (char*)d_ws;
  float* xf = (float*)(ws + 0);                                   // 16 MB
  float* biasbuf = (float*)(ws + 16777216);                       // 8 MB
  unsigned short* wattnT = (unsigned short*)(ws + 25165824);      // 12 MB
  unsigned short* wff1T = (unsigned short*)(ws + 37748736);       // 12 MB
  unsigned short* wff2T = (unsigned short*)(ws + 50331648);       // 12 MB
  unsigned short* lnbuf = (unsigned short*)(ws + 62914560);       // 8 MB
  unsigned short* Qb = (unsigned short*)(ws + 71303168);          // 8 MB
  unsigned short* Kb = (unsigned short*)(ws + 79691776);          // 8 MB
  unsigned short* VTb = (unsigned short*)(ws + 88080384);         // 8 MB
  unsigned short* Ob = (unsigned short*)(ws + 96468992);          // 8 MB
  unsigned short* H1b = Qb;  // 32 MB FF hidden aliases Q/K/VT/O (disjoint lifetimes)
  // total ws use: 100 MB

  const int M = B_ * S_;

  pe_add_kernel<<<(B_ * S_ * D_) / 256, 256, 0, stream>>>(x, coords, cls_pe, xf);
  bias_kernel<<<(S_ * S_) / 256, 256, 0, stream>>>(coords, bias_emb, biasbuf);
  transpose_cvt<<<dim3(16, 16, 24), 256, 0, stream>>>(attn_w, wattnT, 512, 512);
  transpose_cvt<<<dim3(64, 16, 6), 256, 0, stream>>>(ff_w1, wff1T, 512, 2048);
  transpose_cvt<<<dim3(16, 64, 6), 256, 0, stream>>>(ff_w2, wff2T, 2048, 512);

  for (int i = 0; i < NL_; i++) {
    ln_kernel<0><<<M / 4, 256, 0, stream>>>(xf, ln_g + (i * 2 + 0) * D_, ln_b + (i * 2 + 0) * D_, lnbuf);
    gemm_bt<0><<<dim3(4, 64), 256, 0, stream>>>(lnbuf, wattnT + (size_t)(i * 4 + 0) * D_ * D_,
                                                attn_b + (i * 4 + 0) * D_, Qb, nullptr, M, D_, D_);
    gemm_bt<0><<<dim3(4, 64), 256, 0, stream>>>(lnbuf, wattnT + (size_t)(i * 4 + 1) * D_ * D_,
                                                attn_b + (i * 4 + 1) * D_, Kb, nullptr, M, D_, D_);
    gemm_bt<3><<<dim3(4, 64), 256, 0, stream>>>(lnbuf, wattnT + (size_t)(i * 4 + 2) * D_ * D_,
                                                attn_b + (i * 4 + 2) * D_, VTb, nullptr, M, D_, D_);
    attn_kernel<<<dim3(8, B_ * H_), 256, 0, stream>>>(Qb, Kb, VTb, biasbuf, mask, Ob);
    gemm_bt<1><<<dim3(4, 64), 256, 0, stream>>>(Ob, wattnT + (size_t)(i * 4 + 3) * D_ * D_,
                                                attn_b + (i * 4 + 3) * D_, nullptr, xf, M, D_, D_);
    ln_kernel<0><<<M / 4, 256, 0, stream>>>(xf, ln_g + (i * 2 + 1) * D_, ln_b + (i * 2 + 1) * D_, lnbuf);
    gemm_bt<2><<<dim3(16, 64), 256, 0, stream>>>(lnbuf, wff1T + (size_t)i * DFF_ * D_,
                                                 ff_b1 + i * DFF_, H1b, nullptr, M, DFF_, D_);
    gemm_bt<1><<<dim3(4, 64), 256, 0, stream>>>(H1b, wff2T + (size_t)i * D_ * DFF_,
                                                ff_b2 + i * D_, nullptr, xf, M, D_, DFF_);
    if (i == 2) ln_kernel<1><<<M / 4, 256, 0, stream>>>(xf, norm2_g, norm2_b, xf);
  }
  ln_kernel<1><<<M / 4, 256, 0, stream>>>(xf, norm_g, norm_b, (float*)d_out);
}